// Round 1
// baseline (179.488 us; speedup 1.0000x reference)
//
#include <hip/hip_runtime.h>
#include <hip/hip_bf16.h>

// Problem constants (fixed by the reference's setup_inputs)
#define BB 8
#define HH 16
#define SS 1024
#define KK 10          // NUM_TOP
#define NL 8           // num_labels
#define FF (HH * KK)   // 160 features

#define NEG_FLT_MAX (-3.402823466e+38f)

// Sorted-descending top-10 insertion: new_a[k] = clamp(v, a[k], a[k-1]).
// All static register names -> stays in VGPRs. Guard: skip when v can't enter.
#define TOPK_INSERT(v) do {                       \
    if ((v) > a9) {                               \
        a9 = fminf(fmaxf((v), a9), a8);           \
        a8 = fminf(fmaxf((v), a8), a7);           \
        a7 = fminf(fmaxf((v), a7), a6);           \
        a6 = fminf(fmaxf((v), a6), a5);           \
        a5 = fminf(fmaxf((v), a5), a4);           \
        a4 = fminf(fmaxf((v), a4), a3);           \
        a3 = fminf(fmaxf((v), a3), a2);           \
        a2 = fminf(fmaxf((v), a2), a1);           \
        a1 = fminf(fmaxf((v), a1), a0);           \
        a0 = fmaxf(a0, (v));                      \
    }                                             \
} while (0)

// One thread per (b, h, column). Lanes = consecutive columns -> coalesced
// 256B/wave row reads. Walk all S rows, keep top-10 sorted in registers.
__global__ __launch_bounds__(256) void topk_kernel(
        const float* __restrict__ att, float* __restrict__ feats) {
    const int g   = blockIdx.x * 256 + threadIdx.x;  // 0 .. B*H*S-1
    const int bh  = g >> 10;                         // b*H + h   (S = 1024)
    const int col = g & (SS - 1);

    const float* p = att + (size_t)bh * SS * SS + col;

    float a0 = NEG_FLT_MAX, a1 = NEG_FLT_MAX, a2 = NEG_FLT_MAX,
          a3 = NEG_FLT_MAX, a4 = NEG_FLT_MAX, a5 = NEG_FLT_MAX,
          a6 = NEG_FLT_MAX, a7 = NEG_FLT_MAX, a8 = NEG_FLT_MAX,
          a9 = NEG_FLT_MAX;

    for (int j = 0; j < SS; j += 8) {
        const float* q = p + (size_t)j * SS;
        // 8 independent loads issued together for memory-level parallelism
        float v0 = q[0 * SS];
        float v1 = q[1 * SS];
        float v2 = q[2 * SS];
        float v3 = q[3 * SS];
        float v4 = q[4 * SS];
        float v5 = q[5 * SS];
        float v6 = q[6 * SS];
        float v7 = q[7 * SS];
        TOPK_INSERT(v0);
        TOPK_INSERT(v1);
        TOPK_INSERT(v2);
        TOPK_INSERT(v3);
        TOPK_INSERT(v4);
        TOPK_INSERT(v5);
        TOPK_INSERT(v6);
        TOPK_INSERT(v7);
    }

    const int b = bh >> 4;          // H = 16
    const int h = bh & (HH - 1);
    // feats layout: [b][s][h][k]  (s == col), f = h*K + k
    float* o = feats + ((size_t)(b * SS + col) * HH + h) * KK;
    o[0] = a0; o[1] = a1; o[2] = a2; o[3] = a3; o[4] = a4;
    o[5] = a5; o[6] = a6; o[7] = a7; o[8] = a8; o[9] = a9;
}

// Tiny linear layer: one thread per (b, s). W cached in LDS (broadcast reads).
__global__ __launch_bounds__(256) void linear_kernel(
        const float* __restrict__ feats, const float* __restrict__ W,
        const float* __restrict__ bias, float* __restrict__ out) {
    __shared__ float sW[NL * FF];
    __shared__ float sb[NL];
    for (int i = threadIdx.x; i < NL * FF; i += 256) sW[i] = W[i];
    if (threadIdx.x < NL) sb[threadIdx.x] = bias[threadIdx.x];
    __syncthreads();

    const int t = blockIdx.x * 256 + threadIdx.x;   // 0 .. B*S-1

    const float4* f4 = (const float4*)(feats + (size_t)t * FF);
    float acc[NL];
#pragma unroll
    for (int l = 0; l < NL; ++l) acc[l] = sb[l];

#pragma unroll 4
    for (int i = 0; i < FF / 4; ++i) {
        const float4 v = f4[i];
#pragma unroll
        for (int l = 0; l < NL; ++l) {
            const float* w = &sW[l * FF + i * 4];
            acc[l] += v.x * w[0] + v.y * w[1] + v.z * w[2] + v.w * w[3];
        }
    }

    float4* o4 = (float4*)(out + (size_t)t * NL);
    o4[0] = make_float4(acc[0], acc[1], acc[2], acc[3]);
    o4[1] = make_float4(acc[4], acc[5], acc[6], acc[7]);
}

extern "C" void kernel_launch(void* const* d_in, const int* in_sizes, int n_in,
                              void* d_out, int out_size, void* d_ws, size_t ws_size,
                              hipStream_t stream) {
    const float* att  = (const float*)d_in[0];   // (B,H,S,S) fp32
    const float* W    = (const float*)d_in[1];   // (8,160)   fp32
    const float* bias = (const float*)d_in[2];   // (8,)      fp32
    float* out   = (float*)d_out;                // (B,S,8)   fp32
    float* feats = (float*)d_ws;                 // needs B*S*160*4 = 5.25 MB

    topk_kernel<<<(BB * HH * SS) / 256, 256, 0, stream>>>(att, feats);
    linear_kernel<<<(BB * SS) / 256, 256, 0, stream>>>(feats, W, bias, out);
}

// Round 2
// 125.569 us; speedup vs baseline: 1.4294x; 1.4294x over previous
//
#include <hip/hip_runtime.h>
#include <hip/hip_bf16.h>

// Problem constants (fixed by the reference's setup_inputs)
#define BB 8
#define HH 16
#define SS 1024
#define KK 10          // NUM_TOP
#define NL 8           // num_labels
#define FF (HH * KK)   // 160 features
#define NCHUNK 4       // row chunks per column (one wave each)
#define ROWS_PER_CHUNK (SS / NCHUNK)   // 256

#define NEG_FLT_MAX (-3.402823466e+38f)

// Unconditional sorted-descending top-10 insertion.
// new_a[k] = min(max(v, a[k]), a[k-1]); identity when v <= a9, so no guard
// needed (removes branch + divergence; ~19 min/max VALU ops, all static regs).
#define TOPK_CHAIN(v) do {                        \
    const float t_ = (v);                         \
    a9 = fminf(fmaxf(t_, a9), a8);                \
    a8 = fminf(fmaxf(t_, a8), a7);                \
    a7 = fminf(fmaxf(t_, a7), a6);                \
    a6 = fminf(fmaxf(t_, a6), a5);                \
    a5 = fminf(fmaxf(t_, a5), a4);                \
    a4 = fminf(fmaxf(t_, a4), a3);                \
    a3 = fminf(fmaxf(t_, a3), a2);                \
    a2 = fminf(fmaxf(t_, a2), a1);                \
    a1 = fminf(fmaxf(t_, a1), a0);                \
    a0 = fmaxf(a0, t_);                           \
} while (0)

// Block = 256 threads = 4 waves. Each block owns 64 consecutive columns of one
// (b,h) matrix; wave w scans rows [w*256, w*256+256) for those columns
// (lane -> column, fully coalesced 256B/wave row reads). Partial top-10s are
// merged through LDS by wave 0. 2048 blocks = 8 blocks/CU = 8 waves/SIMD.
__global__ __launch_bounds__(256) void topk_kernel(
        const float* __restrict__ att, float* __restrict__ feats) {
    __shared__ float lds[NCHUNK][KK][64];

    const int lane = threadIdx.x & 63;
    const int w    = threadIdx.x >> 6;           // wave index = row chunk
    const int bh   = blockIdx.x >> 4;            // 16 blocks per (b,h)
    const int col  = ((blockIdx.x & 15) << 6) + lane;

    const float* p = att + (size_t)bh * SS * SS
                         + (size_t)(w * ROWS_PER_CHUNK) * SS + col;

    float a0 = NEG_FLT_MAX, a1 = NEG_FLT_MAX, a2 = NEG_FLT_MAX,
          a3 = NEG_FLT_MAX, a4 = NEG_FLT_MAX, a5 = NEG_FLT_MAX,
          a6 = NEG_FLT_MAX, a7 = NEG_FLT_MAX, a8 = NEG_FLT_MAX,
          a9 = NEG_FLT_MAX;

    for (int j = 0; j < ROWS_PER_CHUNK; j += 8) {
        const float* q = p + (size_t)j * SS;
        // 8 independent loads in flight, then 8 chains
        float v0 = q[0 * SS];
        float v1 = q[1 * SS];
        float v2 = q[2 * SS];
        float v3 = q[3 * SS];
        float v4 = q[4 * SS];
        float v5 = q[5 * SS];
        float v6 = q[6 * SS];
        float v7 = q[7 * SS];
        TOPK_CHAIN(v0);
        TOPK_CHAIN(v1);
        TOPK_CHAIN(v2);
        TOPK_CHAIN(v3);
        TOPK_CHAIN(v4);
        TOPK_CHAIN(v5);
        TOPK_CHAIN(v6);
        TOPK_CHAIN(v7);
    }

    // Publish partial top-10 (lane-contiguous -> conflict-free)
    lds[w][0][lane] = a0; lds[w][1][lane] = a1; lds[w][2][lane] = a2;
    lds[w][3][lane] = a3; lds[w][4][lane] = a4; lds[w][5][lane] = a5;
    lds[w][6][lane] = a6; lds[w][7][lane] = a7; lds[w][8][lane] = a8;
    lds[w][9][lane] = a9;
    __syncthreads();

    if (w == 0) {
        // a0..a9 already hold chunk 0's list; fold in chunks 1..3.
        // Union of the 4 partial top-10s contains the global top-10.
#pragma unroll
        for (int c = 1; c < NCHUNK; ++c) {
#pragma unroll
            for (int k = 0; k < KK; ++k) {
                TOPK_CHAIN(lds[c][k][lane]);
            }
        }
        const int b = bh >> 4;          // H = 16
        const int h = bh & (HH - 1);
        float* o = feats + ((size_t)(b * SS + col) * HH + h) * KK;
        o[0] = a0; o[1] = a1; o[2] = a2; o[3] = a3; o[4] = a4;
        o[5] = a5; o[6] = a6; o[7] = a7; o[8] = a8; o[9] = a9;
    }
}

// Tiny linear layer: one thread per (b, s). W cached in LDS (broadcast reads).
__global__ __launch_bounds__(256) void linear_kernel(
        const float* __restrict__ feats, const float* __restrict__ W,
        const float* __restrict__ bias, float* __restrict__ out) {
    __shared__ float sW[NL * FF];
    __shared__ float sb[NL];
    for (int i = threadIdx.x; i < NL * FF; i += 256) sW[i] = W[i];
    if (threadIdx.x < NL) sb[threadIdx.x] = bias[threadIdx.x];
    __syncthreads();

    const int t = blockIdx.x * 256 + threadIdx.x;   // 0 .. B*S-1

    const float4* f4 = (const float4*)(feats + (size_t)t * FF);
    float acc[NL];
#pragma unroll
    for (int l = 0; l < NL; ++l) acc[l] = sb[l];

#pragma unroll 4
    for (int i = 0; i < FF / 4; ++i) {
        const float4 v = f4[i];
#pragma unroll
        for (int l = 0; l < NL; ++l) {
            const float* w = &sW[l * FF + i * 4];
            acc[l] += v.x * w[0] + v.y * w[1] + v.z * w[2] + v.w * w[3];
        }
    }

    float4* o4 = (float4*)(out + (size_t)t * NL);
    o4[0] = make_float4(acc[0], acc[1], acc[2], acc[3]);
    o4[1] = make_float4(acc[4], acc[5], acc[6], acc[7]);
}

extern "C" void kernel_launch(void* const* d_in, const int* in_sizes, int n_in,
                              void* d_out, int out_size, void* d_ws, size_t ws_size,
                              hipStream_t stream) {
    const float* att  = (const float*)d_in[0];   // (B,H,S,S) fp32
    const float* W    = (const float*)d_in[1];   // (8,160)   fp32
    const float* bias = (const float*)d_in[2];   // (8,)      fp32
    float* out   = (float*)d_out;                // (B,S,8)   fp32
    float* feats = (float*)d_ws;                 // needs B*S*160*4 = 5.25 MB

    topk_kernel<<<(BB * HH * SS) / 64, 256, 0, stream>>>(att, feats);
    linear_kernel<<<(BB * SS) / 256, 256, 0, stream>>>(feats, W, bias, out);
}